// Round 4
// baseline (262.109 us; speedup 1.0000x reference)
//
#include <hip/hip_runtime.h>

#define D_IN  128
#define D_OUT 32
#define H     512
#define W     512
#define W4    128          // W/4 float4 lanes per row
#define HB    16           // output H rows per block
#define ZR    (HB + 8)     // z rows incl. h-halo (24)
#define NTHR  512
#define CD    4                     // d-outputs per block (streamed)
#define ZCH   (D_OUT / CD)          // 8 z-chunks
#define CONV_GRID (ZCH * (H / HB))  // 8 * 32 = 256 blocks (1/CU)

// v5: streaming z-chunk conv. Block = (h-tile, 4 consecutive d-outputs).
// The 21 input slices of the chunk window are each read ONCE (requested
// traffic 453->258 MB; v1-v4 showed the conv is bound by a shared per-CU
// memory-path concurrency limit at ~5.6 TB/s of *requested* traffic, not
// HBM and not occupancy). Partial z-conv tiles live in registers (3 rotating
// sets of 6 float4/thread); completed outputs flush through zbuf to the
// proven shuffle-fused h+w conv.
__global__ __launch_bounds__(NTHR)
void conv3d_fused(const float* __restrict__ inp, float* __restrict__ out,
                  const float* __restrict__ bxy_p, const float* __restrict__ bz_p,
                  float* __restrict__ blkMin, float* __restrict__ blkMax) {
    __shared__ float zbuf[ZR * W];   // 48 KiB
    __shared__ float smin[8], smax[8];

    const int tid = threadIdx.x;
    const int h0 = (blockIdx.x & 31) * HB;       // 32 h-tiles
    const int d0 = (blockIdx.x >> 5) * CD;       // 8 z-chunks

    const float bz = bz_p[0], bx = bxy_p[0];
    const float iz = 1.0f / (2.0f * bz * bz);
    const float ix = 1.0f / (2.0f * bx * bx);
    float wz[9], wx[9];
#pragma unroll
    for (int k = 0; k < 9; ++k) {
        float dd = (float)(k - 4);
        wz[k] = expf(-dd * dd * iz);
        wx[k] = expf(-dd * dd * ix);
    }

    const float4* in4 = (const float4*)inp;
    float4* z4 = (float4*)zbuf;

    // Per-thread fixed tile positions: pos_j = j*512 + tid (j=0..5) covers
    // ZR*W4 = 3072 float4. r = pos>>7 is wave-uniform.
    int  rowOff[6];
    bool rowOk[6];
#pragma unroll
    for (int j = 0; j < 6; ++j) {
        int pos = j * NTHR + tid;
        int r   = pos >> 7;
        int c4  = pos & (W4 - 1);
        int h   = h0 - 4 + r;
        rowOk[j]  = (unsigned)h < H;
        rowOff[j] = h * W4 + c4;
    }

    const float4 f4z = make_float4(0.f, 0.f, 0.f, 0.f);

    auto loadSlice = [&](int din, float4 (&v)[6]) {
        if ((unsigned)din < D_IN) {
            const float4* p = in4 + (size_t)din * (H * W4);
#pragma unroll
            for (int j = 0; j < 6; ++j)
                v[j] = rowOk[j] ? p[rowOff[j]] : f4z;
        } else {
#pragma unroll
            for (int j = 0; j < 6; ++j) v[j] = f4z;
        }
    };
    auto fmaSet = [&](float4 (&A)[6], const float4 (&v)[6], float w) {
#pragma unroll
        for (int j = 0; j < 6; ++j) {
            A[j].x += v[j].x * w; A[j].y += v[j].y * w;
            A[j].z += v[j].z * w; A[j].w += v[j].w * w;
        }
    };

    float4 A0[6], A1[6], A2[6];
#pragma unroll
    for (int j = 0; j < 6; ++j) A0[j] = A1[j] = A2[j] = f4z;

    const int z0 = 4 * d0 - 3;
    float4 va[6], vb[6];

    // ---- Prologue: slices k=0..4 of output d0 (slice z0+4 also k'=0 of d0+1)
    loadSlice(z0 + 0, va);
    loadSlice(z0 + 1, vb);
    fmaSet(A0, va, wz[0]);
    loadSlice(z0 + 2, va);
    fmaSet(A0, vb, wz[1]);
    loadSlice(z0 + 3, vb);
    fmaSet(A0, va, wz[2]);
    loadSlice(z0 + 4, va);
    fmaSet(A0, vb, wz[3]);
    fmaSet(A0, va, wz[4]);
    fmaSet(A1, va, wz[0]);

    const int lane = threadIdx.x & 63;
    float lmin =  3.402823466e38f;
    float lmax = -3.402823466e38f;
    float4* out4 = (float4*)out;

#pragma unroll
    for (int i = 0; i < CD; ++i) {
        const int d = d0 + i;
        float4 (&Ac)[6]  = (i % 3 == 0) ? A0 : (i % 3 == 1) ? A1 : A2;
        float4 (&An)[6]  = ((i + 1) % 3 == 0) ? A0 : ((i + 1) % 3 == 1) ? A1 : A2;
        float4 (&An2)[6] = ((i + 2) % 3 == 0) ? A0 : ((i + 2) % 3 == 1) ? A1 : A2;

        // ---- slices k=5..8 of output d (also k-4 of d+1; k=8 is k''=0 of d+2)
        const int b = 4 * d + 2;
        loadSlice(b + 0, va);                       // k=5
        loadSlice(b + 1, vb);                       // k=6
        fmaSet(Ac, va, wz[5]);
        if (i + 1 < CD) fmaSet(An, va, wz[1]);
        loadSlice(b + 2, va);                       // k=7
        fmaSet(Ac, vb, wz[6]);
        if (i + 1 < CD) fmaSet(An, vb, wz[2]);
        loadSlice(b + 3, vb);                       // k=8
        fmaSet(Ac, va, wz[7]);
        if (i + 1 < CD) fmaSet(An, va, wz[3]);
        fmaSet(Ac, vb, wz[8]);
        if (i + 1 < CD) fmaSet(An, vb, wz[4]);
        if (i + 2 < CD) fmaSet(An2, vb, wz[0]);

        // ---- flush output d: regs -> zbuf -> fused h+w conv -> global
        __syncthreads();             // previous flush's zbuf readers done
#pragma unroll
        for (int j = 0; j < 6; ++j) z4[j * NTHR + tid] = Ac[j];
#pragma unroll
        for (int j = 0; j < 6; ++j) Ac[j] = f4z;
        __syncthreads();

        for (int t = tid; t < HB * W4; t += NTHR) {   // 4 iterations
            int r  = t >> 7;            // 0..15 (wave-uniform)
            int c4 = t & (W4 - 1);      // consecutive across lanes

            // h-conv at (r, c4)
            float4 v = f4z;
#pragma unroll
            for (int k = 0; k < 9; ++k) {
                float4 z = z4[(r + k) * W4 + c4];
                v.x += z.x * wx[k]; v.y += z.y * wx[k];
                v.z += z.z * wx[k]; v.w += z.w * wx[k];
            }

            // w-neighbors from adjacent lanes
            float4 vaw, vcw;
            vaw.x = __shfl_up(v.x, 1, 64);   vaw.y = __shfl_up(v.y, 1, 64);
            vaw.z = __shfl_up(v.z, 1, 64);   vaw.w = __shfl_up(v.w, 1, 64);
            vcw.x = __shfl_down(v.x, 1, 64); vcw.y = __shfl_down(v.y, 1, 64);
            vcw.z = __shfl_down(v.z, 1, 64); vcw.w = __shfl_down(v.w, 1, 64);

            // wave-edge lanes recompute neighbor column (OOB -> zero pad)
            if (lane == 0 || lane == 63) {
                int c4n = c4 + ((lane == 0) ? -1 : 1);
                float4 vn = f4z;
                if ((unsigned)c4n < W4) {
#pragma unroll
                    for (int k = 0; k < 9; ++k) {
                        float4 z = z4[(r + k) * W4 + c4n];
                        vn.x += z.x * wx[k]; vn.y += z.y * wx[k];
                        vn.z += z.z * wx[k]; vn.w += z.w * wx[k];
                    }
                }
                if (lane == 0) vaw = vn; else vcw = vn;
            }

            float win[12] = {vaw.x, vaw.y, vaw.z, vaw.w,
                             v.x,   v.y,   v.z,   v.w,
                             vcw.x, vcw.y, vcw.z, vcw.w};
            float4 o = f4z;
#pragma unroll
            for (int k = 0; k < 9; ++k) {
                o.x += win[k]     * wx[k];
                o.y += win[k + 1] * wx[k];
                o.z += win[k + 2] * wx[k];
                o.w += win[k + 3] * wx[k];
            }
            out4[(d * H + h0 + r) * W4 + c4] = o;
            lmin = fminf(lmin, fminf(fminf(o.x, o.y), fminf(o.z, o.w)));
            lmax = fmaxf(lmax, fmaxf(fmaxf(o.x, o.y), fmaxf(o.z, o.w)));
        }
    }

    // ---- block min/max reduction (8 waves) ----
#pragma unroll
    for (int off = 32; off > 0; off >>= 1) {
        lmin = fminf(lmin, __shfl_down(lmin, off, 64));
        lmax = fmaxf(lmax, __shfl_down(lmax, off, 64));
    }
    int wv = threadIdx.x >> 6;  // 0..7
    if (lane == 0) { smin[wv] = lmin; smax[wv] = lmax; }
    __syncthreads();
    if (threadIdx.x == 0) {
        float mn = smin[0], mx = smax[0];
#pragma unroll
        for (int i = 1; i < 8; ++i) { mn = fminf(mn, smin[i]); mx = fmaxf(mx, smax[i]); }
        blkMin[blockIdx.x] = mn;
        blkMax[blockIdx.x] = mx;
    }
}

// Normalize; each block reduces the per-block min/max arrays itself
// (L2-hot, fully parallel) -> no serialized single-block reduce kernel.
#define NORM_NTHR  256
#define NORM_F4_PER_THR 4
#define NORM_GRID  ((D_OUT * H * W4) / (NORM_NTHR * NORM_F4_PER_THR))  // 2048

__global__ __launch_bounds__(NORM_NTHR)
void norm_kernel(const float* __restrict__ in, float* __restrict__ out,
                 const float* __restrict__ blkMin, const float* __restrict__ blkMax) {
    float lmin =  3.402823466e38f;
    float lmax = -3.402823466e38f;
    for (int i = threadIdx.x; i < CONV_GRID; i += NORM_NTHR) {   // 1 iteration
        lmin = fminf(lmin, blkMin[i]);
        lmax = fmaxf(lmax, blkMax[i]);
    }
#pragma unroll
    for (int off = 32; off > 0; off >>= 1) {
        lmin = fminf(lmin, __shfl_down(lmin, off, 64));
        lmax = fmaxf(lmax, __shfl_down(lmax, off, 64));
    }
    __shared__ float smin[4], smax[4];
    int lane = threadIdx.x & 63, wv = threadIdx.x >> 6;
    if (lane == 0) { smin[wv] = lmin; smax[wv] = lmax; }
    __syncthreads();
    float mn  = fminf(fminf(smin[0], smin[1]), fminf(smin[2], smin[3]));
    float mx  = fmaxf(fmaxf(smax[0], smax[1]), fmaxf(smax[2], smax[3]));
    float inv = 1.0f / (mx - mn);

    const float4* in4  = (const float4*)in;
    float4*       out4 = (float4*)out;
    int base = blockIdx.x * (NORM_NTHR * NORM_F4_PER_THR) + threadIdx.x;
#pragma unroll
    for (int j = 0; j < NORM_F4_PER_THR; ++j) {
        int idx = base + j * NORM_NTHR;
        float4 v = in4[idx];
        out4[idx] = make_float4((v.x - mn) * inv, (v.y - mn) * inv,
                                (v.z - mn) * inv, (v.w - mn) * inv);
    }
}

extern "C" void kernel_launch(void* const* d_in, const int* in_sizes, int n_in,
                              void* d_out, int out_size, void* d_ws, size_t ws_size,
                              hipStream_t stream) {
    const float* inp    = (const float*)d_in[0];
    // mu_z / sig_z only produce a positive global scale, which cancels in the
    // min-max normalization -> unused.
    const float* bet_xy = (const float*)d_in[3];
    const float* bet_z  = (const float*)d_in[4];
    float* out = (float*)d_out;

    char* ws = (char*)d_ws;
    float* blkMin = (float*)(ws + 4096);         // 256 floats
    float* blkMax = (float*)(ws + 16384);        // 256 floats
    float* bufA   = (float*)(ws + 65536);        // 32 MiB conv output

    conv3d_fused<<<CONV_GRID, NTHR, 0, stream>>>(inp, bufA, bet_xy, bet_z, blkMin, blkMax);
    norm_kernel<<<NORM_GRID, NORM_NTHR, 0, stream>>>(bufA, out, blkMin, blkMax);
}